// Round 6
// baseline (1554.263 us; speedup 1.0000x reference)
//
#include <hip/hip_runtime.h>

#define HID 16
#define NFEAT 512

__device__ __forceinline__ unsigned short f2b(float f) {
    unsigned u = __float_as_uint(f);
    unsigned r = (u + 0x7fffu + ((u >> 16) & 1u)) >> 16;   // RNE
    return (unsigned short)r;
}
__device__ __forceinline__ float b2f(unsigned short b) {
    return __uint_as_float(((unsigned)b) << 16);
}

// ---------------------------------------------------------------- degree
__global__ __launch_bounds__(256) void deg_count_int(const int* __restrict__ dst,
                                                     int* __restrict__ ideg, int e) {
    int i = blockIdx.x * 256 + threadIdx.x;
    if (i < e) atomicAdd(&ideg[dst[i]], 1);
}

__global__ __launch_bounds__(256) void make_dis(const int* __restrict__ ideg,
                                                float* __restrict__ dis, int n) {
    int i = blockIdx.x * 256 + threadIdx.x;
    if (i < n) dis[i] = rsqrtf(1.0f + (float)ideg[i]);
}

// ---------------------------------------------------------------- h1 = x @ W1
// Block = 256 thr = 16 row-pairs x 16 k-chunks; 2 rows/thread (acc[2][16],
// all statically indexed -> no scratch). One ds_read_b128 of W feeds 2 rows.
// __launch_bounds__(256,2): VGPR cap 128, no spill (round-4 lesson).
// Epilogue writes h1 (fp32) and hs = h1*dis (bf16) for the propagation gather.
__global__ __launch_bounds__(256, 2) void mm1(const float* __restrict__ x,
                                              const float* __restrict__ W1,
                                              const float* __restrict__ dis,
                                              float* __restrict__ h1,
                                              unsigned short* __restrict__ hsb, int n) {
    __shared__ float lds[NFEAT * HID];        // 32 KB: W1t, then reused as red[]
    float* W1t = lds;                         // [16][512]
    for (int idx = threadIdx.x; idx < NFEAT * HID / 4; idx += 256) {
        int k = idx >> 2, j0 = (idx & 3) * 4;
        float4 v = ((const float4*)W1)[idx];
        W1t[(j0 + 0) * NFEAT + k] = v.x;
        W1t[(j0 + 1) * NFEAT + k] = v.y;
        W1t[(j0 + 2) * NFEAT + k] = v.z;
        W1t[(j0 + 3) * NFEAT + k] = v.w;
    }
    __syncthreads();

    int r = threadIdx.x >> 4;                 // 0..15 row-pair
    int c = threadIdx.x & 15;                 // k-chunk
    int row0 = blockIdx.x * 32 + r * 2;
    bool a0 = (row0 < n), a1 = (row0 + 1 < n);

    float acc0[HID], acc1[HID];
#pragma unroll
    for (int j = 0; j < HID; ++j) { acc0[j] = 0.f; acc1[j] = 0.f; }

    const float4* xb = (const float4*)x;
    const float4 z4 = make_float4(0.f, 0.f, 0.f, 0.f);
#pragma unroll
    for (int i = 0; i < 8; ++i) {
        float4 xv0 = a0 ? xb[(size_t)row0 * (NFEAT / 4) + i * 16 + c] : z4;
        float4 xv1 = a1 ? xb[(size_t)(row0 + 1) * (NFEAT / 4) + i * 16 + c] : z4;
        int kb = i * 64 + c * 4;
#pragma unroll
        for (int j = 0; j < HID; ++j) {
            float4 w = *(const float4*)&W1t[j * NFEAT + kb];
            acc0[j] += xv0.x * w.x + xv0.y * w.y + xv0.z * w.z + xv0.w * w.w;
            acc1[j] += xv1.x * w.x + xv1.y * w.y + xv1.z * w.z + xv1.w * w.w;
        }
    }
    __syncthreads();   // done with W1t; reuse lds as red[16][16][17]

    float* red = lds;
#pragma unroll
    for (int q = 0; q < 2; ++q) {
#pragma unroll
        for (int j = 0; j < HID; ++j)
            red[r * 272 + c * 17 + j] = (q == 0) ? acc0[j] : acc1[j];
        __syncthreads();
        float sum = 0.f;
#pragma unroll
        for (int cc = 0; cc < 16; ++cc)
            sum += red[r * 272 + cc * 17 + c];
        int row = row0 + q;
        if (row < n) {
            h1[(size_t)row * HID + c] = sum;
            hsb[(size_t)row * HID + c] = f2b(sum * dis[row]);
        }
        __syncthreads();
    }
}

// ---------------------------------------------------------------- propagation
// agg[d][j] += hs[s][j] — 16 consecutive lanes per edge, ONE atomic per lane:
// the 16 same-line atomics coalesce into a single line-RMW per edge (measured:
// this pattern is 3.7x faster than 4x serial atomics per lane).
__global__ __launch_bounds__(256) void prop(const int* __restrict__ src,
                                            const int* __restrict__ dst,
                                            const unsigned short* __restrict__ hsb,
                                            float* __restrict__ agg, int e) {
    int idx = blockIdx.x * 256 + threadIdx.x;   // e*16 = 51.2M < 2^31
    int ed = idx >> 4, j = idx & 15;
    if (ed >= e) return;
    int s = src[ed], d = dst[ed];
    atomicAdd(&agg[(size_t)d * HID + j], b2f(hsb[(size_t)s * HID + j]));
}

// ---------------------------------------------------------------- fused middle
// h = relu(dis*agg1 + dis^2*h1 + b1);  h2 = h @ W2; h2 -> h1, hs2 -> hsb
__global__ __launch_bounds__(256) void mid(const float* __restrict__ agg1,
                                           float* __restrict__ h1,
                                           unsigned short* __restrict__ hsb,
                                           const float* __restrict__ dis,
                                           const float* __restrict__ b1,
                                           const float* __restrict__ W2, int n) {
    __shared__ float W2s[HID * HID];
    W2s[threadIdx.x] = W2[threadIdx.x];
    __syncthreads();

    int idx = blockIdx.x * 256 + threadIdx.x;
    int v = idx >> 4, j = idx & 15;
    if (v >= n) return;
    float dn = dis[v];
    float a = dn * agg1[idx] + dn * dn * h1[idx] + b1[j];
    float hv = fmaxf(a, 0.f);
    float h2 = 0.f;
#pragma unroll
    for (int k = 0; k < HID; ++k)
        h2 += __shfl(hv, k, HID) * W2s[k * HID + j];
    h1[idx] = h2;
    hsb[idx] = f2b(h2 * dn);
}

// z = dis*agg2 + dis^2*h2 + b2;  out = z + eps*exp(0.5*z)  (agg2 lives in d_out)
__global__ __launch_bounds__(256) void finalk(float* __restrict__ out,
                                              const float* __restrict__ h2,
                                              const float* __restrict__ dis,
                                              const float* __restrict__ b2,
                                              const float* __restrict__ eps, int n) {
    int idx = blockIdx.x * 256 + threadIdx.x;
    int v = idx >> 4, j = idx & 15;
    if (v >= n) return;
    float dn = dis[v];
    float z = dn * out[idx] + dn * dn * h2[idx] + b2[j];
    out[idx] = z + eps[idx] * expf(0.5f * z);
}

extern "C" void kernel_launch(void* const* d_in, const int* in_sizes, int n_in,
                              void* d_out, int out_size, void* d_ws, size_t ws_size,
                              hipStream_t stream) {
    const float* x   = (const float*)d_in[0];
    const float* W1  = (const float*)d_in[1];
    const float* b1  = (const float*)d_in[2];
    const float* W2  = (const float*)d_in[3];
    const float* b2  = (const float*)d_in[4];
    const float* eps = (const float*)d_in[5];
    const int*   ei  = (const int*)d_in[6];

    int n = in_sizes[5] / HID;   // 100000
    int e = in_sizes[6] / 2;     // 3200000
    const int* srcs = ei;
    const int* dsts = ei + e;

    // ws layout: [ideg n int][dis n f32][h1 16n f32][agg1 16n f32][hsb 16n u16]
    int*            ideg = (int*)d_ws;
    float*          dis  = (float*)(ideg + n);
    float*          h1   = dis + n;
    float*          agg1 = h1 + (size_t)n * HID;
    unsigned short* hsb  = (unsigned short*)(agg1 + (size_t)n * HID);
    float*          outf = (float*)d_out;

    size_t featBytes = (size_t)n * HID * sizeof(float);
    hipMemsetAsync(ideg, 0, (size_t)n * sizeof(int), stream);
    hipMemsetAsync(agg1, 0, featBytes, stream);
    hipMemsetAsync(outf, 0, featBytes, stream);

    int nBlk    = (n + 255) / 256;
    int eBlk    = (e + 255) / 256;
    int mmBlk   = (n + 31) / 32;
    int featBlk = (n * 16 + 255) / 256;
    int propBlk = (e * 16 + 255) / 256;

    deg_count_int<<<eBlk, 256, 0, stream>>>(dsts, ideg, e);
    make_dis<<<nBlk, 256, 0, stream>>>(ideg, dis, n);

    mm1<<<mmBlk, 256, 0, stream>>>(x, W1, dis, h1, hsb, n);

    prop<<<propBlk, 256, 0, stream>>>(srcs, dsts, hsb, agg1, e);
    mid<<<featBlk, 256, 0, stream>>>(agg1, h1, hsb, dis, b1, W2, n);
    prop<<<propBlk, 256, 0, stream>>>(srcs, dsts, hsb, outf, e);
    finalk<<<featBlk, 256, 0, stream>>>(outf, h1, dis, b2, eps, n);
}

// Round 7
// 533.125 us; speedup vs baseline: 2.9154x; 2.9154x over previous
//
#include <hip/hip_runtime.h>
#include <hip/hip_bf16.h>

#define HID 16
#define NFEAT 512

typedef __attribute__((ext_vector_type(8))) short bf16x8;
typedef __attribute__((ext_vector_type(4))) float f32x4;

__device__ __forceinline__ unsigned short f2b_hw(float f) {
    __hip_bfloat16 h = __float2bfloat16(f);   // HW RNE convert
    return *reinterpret_cast<unsigned short*>(&h);
}
__device__ __forceinline__ float b2f(unsigned short b) {
    return __uint_as_float(((unsigned)b) << 16);
}

// ---------------------------------------------------------------- degree
__global__ __launch_bounds__(256) void deg_count_int(const int* __restrict__ dst,
                                                     int* __restrict__ ideg, int e) {
    int i = blockIdx.x * 256 + threadIdx.x;
    if (i < e) atomicAdd(&ideg[dst[i]], 1);
}

__global__ __launch_bounds__(256) void make_dis(const int* __restrict__ ideg,
                                                float* __restrict__ dis, int n) {
    int i = blockIdx.x * 256 + threadIdx.x;
    if (i < n) dis[i] = rsqrtf(1.0f + (float)ideg[i]);
}

// ---------------------------------------------------------------- W1 -> Wt (bf16, transposed)
__global__ __launch_bounds__(256) void prep_wt(const float* __restrict__ W1,
                                               unsigned short* __restrict__ Wt) {
    int i = blockIdx.x * 256 + threadIdx.x;   // 8192 = 16*512
    int j = i >> 9, k = i & 511;
    Wt[i] = f2b_hw(W1[k * HID + j]);          // Wt[j][k] = W1[k][j]
}

// ---------------------------------------------------------------- h1 = x @ W1 via MFMA
// One wave per 16-row tile. 16 x mfma_f32_16x16x32_bf16 over K=512.
// A-frag: lane holds x[row = lane&15][t*32 + (lane>>4)*8 .. +8] (fp32->bf16 in reg).
// B-frag: lane holds Wt[j = lane&15][same k-slice]; all 16 staged in VGPRs once.
// A and B share the same per-lane k-run mapping, so the dot product is exact
// regardless of the HW's internal k permutation. C: col=lane&15, row=(lane>>4)*4+q.
__global__ __launch_bounds__(256) void mm1_mfma(const float* __restrict__ x,
                                                const unsigned short* __restrict__ Wt,
                                                const float* __restrict__ dis,
                                                float* __restrict__ h1,
                                                unsigned short* __restrict__ hsb, int n) {
    int wid  = threadIdx.x >> 6;
    int lane = threadIdx.x & 63;
    int base = (blockIdx.x * 4 + wid) * 16;
    if (base >= n) return;
    int lrow = lane & 15;
    int kg   = lane >> 4;                     // 0..3

    bf16x8 bfr[16];
#pragma unroll
    for (int t = 0; t < 16; ++t)
        bfr[t] = *(const bf16x8*)(Wt + lrow * NFEAT + t * 32 + kg * 8);

    int row = base + lrow;
    bool ok = (row < n);
    const float* xr = x + (size_t)(ok ? row : 0) * NFEAT;

    f32x4 acc = {0.f, 0.f, 0.f, 0.f};
#pragma unroll
    for (int t = 0; t < 16; ++t) {
        float4 u0 = *(const float4*)(xr + t * 32 + kg * 8);
        float4 u1 = *(const float4*)(xr + t * 32 + kg * 8 + 4);
        if (!ok) { u0 = make_float4(0,0,0,0); u1 = make_float4(0,0,0,0); }
        union { bf16x8 v; unsigned short u[8]; } A;
        A.u[0] = f2b_hw(u0.x); A.u[1] = f2b_hw(u0.y);
        A.u[2] = f2b_hw(u0.z); A.u[3] = f2b_hw(u0.w);
        A.u[4] = f2b_hw(u1.x); A.u[5] = f2b_hw(u1.y);
        A.u[6] = f2b_hw(u1.z); A.u[7] = f2b_hw(u1.w);
        acc = __builtin_amdgcn_mfma_f32_16x16x32_bf16(A.v, bfr[t], acc, 0, 0, 0);
    }

#pragma unroll
    for (int q = 0; q < 4; ++q) {
        int orow = base + kg * 4 + q;
        if (orow < n) {
            float v = acc[q];
            h1[(size_t)orow * HID + lrow] = v;
            hsb[(size_t)orow * HID + lrow] = f2b_hw(v * dis[orow]);
        }
    }
}

// ---------------------------------------------------------------- propagation
// agg[d][j] += hs[s][j] — 16 consecutive lanes per edge, one atomic per lane:
// same-line atomics coalesce into one line-RMW per edge (measured 3.7x faster
// than split patterns).
__global__ __launch_bounds__(256) void prop(const int* __restrict__ src,
                                            const int* __restrict__ dst,
                                            const unsigned short* __restrict__ hsb,
                                            float* __restrict__ agg, int e) {
    int idx = blockIdx.x * 256 + threadIdx.x;   // e*16 = 51.2M < 2^31
    int ed = idx >> 4, j = idx & 15;
    if (ed >= e) return;
    int s = src[ed], d = dst[ed];
    atomicAdd(&agg[(size_t)d * HID + j], b2f(hsb[(size_t)s * HID + j]));
}

// ---------------------------------------------------------------- fused middle
// h = relu(dis*agg1 + dis^2*h1 + b1);  h2 = h @ W2; h2 -> h1, hs2 -> hsb
__global__ __launch_bounds__(256) void mid(const float* __restrict__ agg1,
                                           float* __restrict__ h1,
                                           unsigned short* __restrict__ hsb,
                                           const float* __restrict__ dis,
                                           const float* __restrict__ b1,
                                           const float* __restrict__ W2, int n) {
    __shared__ float W2s[HID * HID];
    W2s[threadIdx.x] = W2[threadIdx.x];
    __syncthreads();

    int idx = blockIdx.x * 256 + threadIdx.x;
    int v = idx >> 4, j = idx & 15;
    if (v >= n) return;
    float dn = dis[v];
    float a = dn * agg1[idx] + dn * dn * h1[idx] + b1[j];
    float hv = fmaxf(a, 0.f);
    float h2 = 0.f;
#pragma unroll
    for (int k = 0; k < HID; ++k)
        h2 += __shfl(hv, k, HID) * W2s[k * HID + j];
    h1[idx] = h2;
    hsb[idx] = f2b_hw(h2 * dn);
}

// z = dis*agg2 + dis^2*h2 + b2;  out = z + eps*exp(0.5*z)  (agg2 lives in d_out)
__global__ __launch_bounds__(256) void finalk(float* __restrict__ out,
                                              const float* __restrict__ h2,
                                              const float* __restrict__ dis,
                                              const float* __restrict__ b2,
                                              const float* __restrict__ eps, int n) {
    int idx = blockIdx.x * 256 + threadIdx.x;
    int v = idx >> 4, j = idx & 15;
    if (v >= n) return;
    float dn = dis[v];
    float z = dn * out[idx] + dn * dn * h2[idx] + b2[j];
    out[idx] = z + eps[idx] * expf(0.5f * z);
}

extern "C" void kernel_launch(void* const* d_in, const int* in_sizes, int n_in,
                              void* d_out, int out_size, void* d_ws, size_t ws_size,
                              hipStream_t stream) {
    const float* x   = (const float*)d_in[0];
    const float* W1  = (const float*)d_in[1];
    const float* b1  = (const float*)d_in[2];
    const float* W2  = (const float*)d_in[3];
    const float* b2  = (const float*)d_in[4];
    const float* eps = (const float*)d_in[5];
    const int*   ei  = (const int*)d_in[6];

    int n = in_sizes[5] / HID;   // 100000
    int e = in_sizes[6] / 2;     // 3200000
    const int* srcs = ei;
    const int* dsts = ei + e;

    // ws: [ideg n int][dis n f32][h1 16n f32][agg1 16n f32][hsb 16n u16][Wt 8192 u16]
    int*            ideg = (int*)d_ws;
    float*          dis  = (float*)(ideg + n);
    float*          h1   = dis + n;
    float*          agg1 = h1 + (size_t)n * HID;
    unsigned short* hsb  = (unsigned short*)(agg1 + (size_t)n * HID);
    unsigned short* Wt   = hsb + (size_t)n * HID;
    float*          outf = (float*)d_out;

    size_t featBytes = (size_t)n * HID * sizeof(float);
    hipMemsetAsync(ideg, 0, (size_t)n * sizeof(int), stream);
    hipMemsetAsync(agg1, 0, featBytes, stream);
    hipMemsetAsync(outf, 0, featBytes, stream);

    int nBlk    = (n + 255) / 256;
    int eBlk    = (e + 255) / 256;
    int mmBlk   = (n + 63) / 64;
    int featBlk = (n * 16 + 255) / 256;
    int propBlk = (e * 16 + 255) / 256;

    prep_wt<<<32, 256, 0, stream>>>(W1, Wt);
    deg_count_int<<<eBlk, 256, 0, stream>>>(dsts, ideg, e);
    make_dis<<<nBlk, 256, 0, stream>>>(ideg, dis, n);

    mm1_mfma<<<mmBlk, 256, 0, stream>>>(x, Wt, dis, h1, hsb, n);

    prop<<<propBlk, 256, 0, stream>>>(srcs, dsts, hsb, agg1, e);
    mid<<<featBlk, 256, 0, stream>>>(agg1, h1, hsb, dis, b1, W2, n);
    prop<<<propBlk, 256, 0, stream>>>(srcs, dsts, hsb, outf, e);
    finalk<<<featBlk, 256, 0, stream>>>(outf, h1, dis, b2, eps, n);
}